// Round 1
// baseline (31.158 us; speedup 1.0000x reference)
//
#include <hip/hip_runtime.h>

#define B_DIM 2048
#define F_DIM 512
#define U_DIM 256
#define M_HALF 128

// K = beta * log2(e), so beta*(x+w) in log2-domain is K*(x+w)
constexpr float K_L2E = 21.64042561333445f;   // 15 * log2(e)
constexpr float INV_K = 1.0f / K_L2E;         // ln2 / 15

// ---------------- kernel 1: per-row max/min of x ----------------
__global__ __launch_bounds__(256)
void rowstat_k(const float* __restrict__ x,
               float* __restrict__ mx, float* __restrict__ mn) {
    const int b = blockIdx.x;
    const int tid = threadIdx.x;
    float2 v = reinterpret_cast<const float2*>(x + b * F_DIM)[tid];
    float hi = fmaxf(v.x, v.y);
    float lo = fminf(v.x, v.y);
#pragma unroll
    for (int off = 32; off; off >>= 1) {
        hi = fmaxf(hi, __shfl_xor(hi, off));
        lo = fminf(lo, __shfl_xor(lo, off));
    }
    __shared__ float smx[4], smn[4];
    if ((tid & 63) == 0) { smx[tid >> 6] = hi; smn[tid >> 6] = lo; }
    __syncthreads();
    if (tid == 0) {
        mx[b] = fmaxf(fmaxf(smx[0], smx[1]), fmaxf(smx[2], smx[3]));
        mn[b] = fminf(fminf(smn[0], smn[1]), fminf(smn[2], smn[3]));
    }
}

// ---------------- kernel 2: fused exp + GEMM + log ----------------
#define BT_B 32
#define BT_U 64
#define FK   32

__global__ __launch_bounds__(256)
void smm_k(const float* __restrict__ x, const float* __restrict__ w,
           const float* __restrict__ mx, const float* __restrict__ mn,
           float* __restrict__ out) {
    // transposed x-exp tile so the 2 row-values per thread are adjacent (b64 read)
    __shared__ float sExT[FK][BT_B + 2];   // stride 34 floats (136 B, 8B-aligned rows)
    __shared__ float sEw[FK][BT_U + 4];    // stride 68 floats (272 B, 16B-aligned rows)
    __shared__ float srow[BT_B];

    const int tid = threadIdx.x;
    const int b0 = blockIdx.x * BT_B;
    const int u0 = blockIdx.y * BT_U;
    const bool lo_mode = (u0 >= M_HALF);   // whole u-tile is on one side of M

    if (tid < BT_B) srow[tid] = lo_mode ? mn[b0 + tid] : mx[b0 + tid];

    const int cx = tid & 15;   // 16 col groups * 4 cols
    const int ry = tid >> 4;   // 16 row groups * 2 rows
    const int c0 = cx << 2;
    const int r0 = ry << 1;

    float acc[2][4] = {{0.f, 0.f, 0.f, 0.f}, {0.f, 0.f, 0.f, 0.f}};

    for (int f0 = 0; f0 < F_DIM; f0 += FK) {
        __syncthreads();   // protect LDS from previous iteration's readers
        // stage x tile (32 rows x 32 f), exp-transformed, transposed: 4 elems/thread
#pragma unroll
        for (int i = 0; i < 4; ++i) {
            int e = tid + (i << 8);
            int r = e >> 5, f = e & 31;
            float xv = x[(b0 + r) * F_DIM + f0 + f];
            float st = srow[r];
            float arg = lo_mode ? (st - xv) : (xv - st);   // <= 0
            sExT[f][r] = exp2f(K_L2E * arg);
        }
        // stage w tile (32 f x 64 u), exp-transformed: 8 elems/thread
#pragma unroll
        for (int i = 0; i < 8; ++i) {
            int e = tid + (i << 8);
            int f = e >> 6, u = e & 63;
            float wv = w[(f0 + f) * U_DIM + u0 + u];
            sEw[f][u] = exp2f(lo_mode ? (-K_L2E * wv) : (K_L2E * wv));
        }
        __syncthreads();
#pragma unroll
        for (int kk = 0; kk < FK; ++kk) {
            float2 a  = *reinterpret_cast<const float2*>(&sExT[kk][r0]);
            float4 bv = *reinterpret_cast<const float4*>(&sEw[kk][c0]);
            acc[0][0] = fmaf(a.x, bv.x, acc[0][0]);
            acc[0][1] = fmaf(a.x, bv.y, acc[0][1]);
            acc[0][2] = fmaf(a.x, bv.z, acc[0][2]);
            acc[0][3] = fmaf(a.x, bv.w, acc[0][3]);
            acc[1][0] = fmaf(a.y, bv.x, acc[1][0]);
            acc[1][1] = fmaf(a.y, bv.y, acc[1][1]);
            acc[1][2] = fmaf(a.y, bv.z, acc[1][2]);
            acc[1][3] = fmaf(a.y, bv.w, acc[1][3]);
        }
    }

#pragma unroll
    for (int r = 0; r < 2; ++r) {
        float st = srow[r0 + r];
#pragma unroll
        for (int c = 0; c < 4; ++c) {
            float lg = __log2f(acc[r][c]) * INV_K;
            out[(b0 + r0 + r) * U_DIM + u0 + c0 + c] = lo_mode ? (st - lg) : (st + lg);
        }
    }
}

extern "C" void kernel_launch(void* const* d_in, const int* in_sizes, int n_in,
                              void* d_out, int out_size, void* d_ws, size_t ws_size,
                              hipStream_t stream) {
    const float* x = (const float*)d_in[0];
    const float* w = (const float*)d_in[1];
    float* out = (float*)d_out;
    float* mx = (float*)d_ws;          // 2048 floats
    float* mn = mx + B_DIM;            // 2048 floats

    rowstat_k<<<B_DIM, 256, 0, stream>>>(x, mx, mn);
    dim3 grid(B_DIM / BT_B, U_DIM / BT_U);
    smm_k<<<grid, 256, 0, stream>>>(x, w, mx, mn, out);
}

// Round 2
// 14.411 us; speedup vs baseline: 2.1621x; 2.1621x over previous
//
#include <hip/hip_runtime.h>

#define B_DIM 2048
#define F_DIM 512
#define U_DIM 256

constexpr float K_L2E = 21.64042561333445f;   // 15 * log2(e)
constexpr float INV_K = 1.0f / K_L2E;

using short8 = __attribute__((ext_vector_type(8))) short;  // 8 bf16 = 4 VGPRs
using f32x4  = __attribute__((ext_vector_type(4))) float;

__device__ __forceinline__ unsigned short f2bf(float f) {
    unsigned u = __float_as_uint(f);
    return (unsigned short)((u + 0x7FFFu + ((u >> 16) & 1u)) >> 16);  // RNE, finite inputs
}

// ---------------- kernel 1: row stats + exp-fragmented A (both modes) + exp-fragmented B ----
// EA frag layout (per MFMA 16x16x32 A): chunk index ((m*128 + rt)*16 + kb)*64 + lane,
// lane = (b%16) + 16*g, holding 8 bf16 at k = 8*g + i  (f = 32*kb + 8*g + i)
// EW frag layout (B): chunk index (ut*16 + kb)*64 + lane, lane = (u%16) + 16*g, same k mapping.
__global__ __launch_bounds__(256)
void prep_k(const float* __restrict__ x, const float* __restrict__ w,
            float* __restrict__ mx, float* __restrict__ mn,
            unsigned short* __restrict__ ea, unsigned short* __restrict__ ew) {
    const int tid  = threadIdx.x;
    const int wv   = tid >> 6;
    const int lane = tid & 63;
    const int b    = (blockIdx.x << 2) + wv;   // 4 rows per block, one per wave

    // lane holds f = 8*lane .. 8*lane+7  (64 lanes * 8 = 512 = F_DIM)
    const float4* xr = reinterpret_cast<const float4*>(x + b * F_DIM);
    float4 v0 = xr[lane * 2];
    float4 v1 = xr[lane * 2 + 1];
    float f8[8] = {v0.x, v0.y, v0.z, v0.w, v1.x, v1.y, v1.z, v1.w};
    float hi = f8[0], lo = f8[0];
#pragma unroll
    for (int i = 1; i < 8; ++i) { hi = fmaxf(hi, f8[i]); lo = fminf(lo, f8[i]); }
#pragma unroll
    for (int off = 32; off; off >>= 1) {
        hi = fmaxf(hi, __shfl_xor(hi, off));
        lo = fminf(lo, __shfl_xor(lo, off));
    }
    if (lane == 0) { mx[b] = hi; mn[b] = lo; }

    const int rt = b >> 4, br = b & 15;
    const int kb = lane >> 2, g = lane & 3;    // f = 8*lane = 32*kb + 8*g
    const int chunk_lane = br + (g << 4);
    {   // mode 0 (softmax side): exp2(K*(x - max)) <= 1
        short8 c;
#pragma unroll
        for (int i = 0; i < 8; ++i) c[i] = (short)f2bf(exp2f(K_L2E * (f8[i] - hi)));
        reinterpret_cast<short8*>(ea)[(rt * 16 + kb) * 64 + chunk_lane] = c;
    }
    {   // mode 1 (softmin side): exp2(K*(min - x)) <= 1
        short8 c;
#pragma unroll
        for (int i = 0; i < 8; ++i) c[i] = (short)f2bf(exp2f(K_L2E * (lo - f8[i])));
        reinterpret_cast<short8*>(ea)[((128 + rt) * 16 + kb) * 64 + chunk_lane] = c;
    }

    // B-operand transform: blocks 0..255 handle w rows f = 2*bid, 2*bid+1
    if (blockIdx.x < 256) {
        int e  = tid << 1;                      // 512 elems = 2 f-rows * 256 u
        int f  = (blockIdx.x << 1) + (e >> 8);
        int u0 = e & 255;
        float2 wv2 = *reinterpret_cast<const float2*>(w + f * U_DIM + u0);
        const int kbw = f >> 5, gw = (f >> 3) & 3, iw = f & 7;
        float wa[2] = {wv2.x, wv2.y};
#pragma unroll
        for (int j = 0; j < 2; ++j) {
            int u = u0 + j;
            float s = (u < 128) ? K_L2E : -K_L2E;
            int ut = u >> 4;
            int idx = (((ut * 16 + kbw) * 64) + (u & 15) + (gw << 4)) * 8 + iw;
            ew[idx] = f2bf(exp2f(s * wa[j]));
        }
    }
}

// ---------------- kernel 2: pure MFMA GEMM + log epilogue (no LDS, no syncthreads) --------
__global__ __launch_bounds__(256)
void mfma_k(const unsigned short* __restrict__ ea, const unsigned short* __restrict__ ew,
            const float* __restrict__ mx, const float* __restrict__ mn,
            float* __restrict__ out) {
    const int bid  = blockIdx.x;
    const int rt   = bid >> 2;            // 128 row tiles
    const int utq  = bid & 3;
    const int wv   = threadIdx.x >> 6;
    const int lane = threadIdx.x & 63;
    const int ut   = (utq << 2) + wv;     // 16 u tiles, one per wave
    const int m    = (ut >= 8);           // 0 = softmax half, 1 = softmin half

    const short8* A  = reinterpret_cast<const short8*>(ea) + ((m * 128 + rt) * 16) * 64 + lane;
    const short8* Bp = reinterpret_cast<const short8*>(ew) + (ut * 16) * 64 + lane;

    f32x4 acc = {0.f, 0.f, 0.f, 0.f};
#pragma unroll
    for (int kb = 0; kb < 16; ++kb)
        acc = __builtin_amdgcn_mfma_f32_16x16x32_bf16(A[kb * 64], Bp[kb * 64], acc, 0, 0, 0);

    // C/D layout (m89-verified): col = lane&15, row = (lane>>4)*4 + r
    const int j    = lane & 15;
    const int quad = lane >> 4;
    const float* st = m ? mn : mx;
    const int brow = rt * 16 + (quad << 2);
#pragma unroll
    for (int r = 0; r < 4; ++r) {
        float lg = __log2f(acc[r]) * INV_K;
        float sv = st[brow + r];
        out[(brow + r) * U_DIM + (ut << 4) + j] = m ? (sv - lg) : (sv + lg);
    }
}

extern "C" void kernel_launch(void* const* d_in, const int* in_sizes, int n_in,
                              void* d_out, int out_size, void* d_ws, size_t ws_size,
                              hipStream_t stream) {
    const float* x = (const float*)d_in[0];
    const float* w = (const float*)d_in[1];
    float* out = (float*)d_out;
    float* mx = (float*)d_ws;                              // 2048 f32
    float* mn = mx + B_DIM;                                // 2048 f32
    unsigned short* ea = (unsigned short*)((char*)d_ws + 16384);   // 2*128*16*64*8 bf16 = 4 MB
    unsigned short* ew = ea + 2 * 128 * 16 * 64 * 8;               // 16*16*64*8 bf16 = 256 KB

    prep_k<<<512, 256, 0, stream>>>(x, w, mx, mn, ea, ew);
    mfma_k<<<512, 256, 0, stream>>>(ea, ew, mx, mn, out);
}